// Round 3
// baseline (821.381 us; speedup 1.0000x reference)
//
#include <hip/hip_runtime.h>
#include <hip/hip_bf16.h>
#include <stdint.h>

#define B_SZ 4
#define C_IN 256
#define N_SP 4096
#define HEADS 4
#define DH 32
#define HID 128
#define O_QKV 384

#define BI 64
#define BJ 64

// ---------------- Kernel 1: QKV projection (fp32 in, fp32 ws out) ----------------
// qkv[b][o][n] = sum_c w[o][c] * x[b][c][n]
__global__ __launch_bounds__(256) void qkv_proj_k(
    const float* __restrict__ x,
    const float* __restrict__ w,
    float* __restrict__ qkv) {
  const int t = threadIdx.x;
  const int n0 = blockIdx.x * 512 + t * 2;
  const int o0 = blockIdx.y * 8;
  const int b = blockIdx.z;
  const float* xb = x + (size_t)b * C_IN * N_SP + n0;
  float acc0[8], acc1[8];
#pragma unroll
  for (int r = 0; r < 8; ++r) { acc0[r] = 0.f; acc1[r] = 0.f; }
  for (int c = 0; c < C_IN; c += 2) {
    const float2 xa = *(const float2*)(xb + (size_t)c * N_SP);
    const float2 xc = *(const float2*)(xb + (size_t)(c + 1) * N_SP);
#pragma unroll
    for (int r = 0; r < 8; ++r) {
      const float2 wv = *(const float2*)(w + (size_t)(o0 + r) * C_IN + c);
      acc0[r] += wv.x * xa.x + wv.y * xc.x;
      acc1[r] += wv.x * xa.y + wv.y * xc.y;
    }
  }
  float* outp = qkv + ((size_t)b * O_QKV + o0) * N_SP + n0;
#pragma unroll
  for (int r = 0; r < 8; ++r) {
    *(float2*)(outp + (size_t)r * N_SP) = make_float2(acc0[r], acc1[r]);
  }
}

// ---------------- Kernel 2: flash attention (fp32) ----------------
__global__ __launch_bounds__(256) void attn_k(
    const float* __restrict__ qkv, float* __restrict__ att) {
  __shared__ float Qs[DH][BI];        // [d][ii]
  __shared__ float Ks[DH][BJ];        // [d][jj]
  __shared__ float Vt[BJ][DH + 2];    // [jj][d]
  __shared__ float Ps[BJ][BI + 4];    // P^T [jj][ii]
  const int t = threadIdx.x;
  const int ithr = t >> 4, jthr = t & 15;
  const int ii0 = ithr * 4, jj0 = jthr * 4, d0 = jthr * 2;
  const int i0 = blockIdx.x * BI;
  const int bh = blockIdx.y;
  const int b = bh >> 2, h = bh & 3;
  const float* qp = qkv + ((size_t)b * O_QKV + h * DH) * N_SP;
  const float* kp = qp + (size_t)HID * N_SP;
  const float* vp = qp + (size_t)2 * HID * N_SP;
  const float scale = 0.17677669529663687f;  // 32^-0.5

#pragma unroll
  for (int e = 0; e < 8; ++e) {
    const int idx = e * 256 + t;
    const int d = idx >> 6, ii = idx & 63;
    Qs[d][ii] = qp[(size_t)d * N_SP + i0 + ii] * scale;
  }

  float m_i[4], l_i[4], o0a[4], o1a[4];
#pragma unroll
  for (int a = 0; a < 4; ++a) { m_i[a] = -1e30f; l_i[a] = 0.f; o0a[a] = 0.f; o1a[a] = 0.f; }

  for (int jt0 = 0; jt0 < N_SP; jt0 += BJ) {
    __syncthreads();  // protect Ks/Vt/Ps from previous iteration's readers
#pragma unroll
    for (int e = 0; e < 8; ++e) {
      const int idx = e * 256 + t;
      const int d = idx >> 6, jj = idx & 63;
      Ks[d][jj] = kp[(size_t)d * N_SP + jt0 + jj];
      Vt[jj][d] = vp[(size_t)d * N_SP + jt0 + jj];
    }
    __syncthreads();

    float s[4][4];
#pragma unroll
    for (int a = 0; a < 4; ++a)
#pragma unroll
      for (int c2 = 0; c2 < 4; ++c2) s[a][c2] = 0.f;
#pragma unroll
    for (int d = 0; d < DH; ++d) {
      const float4 qv = *(const float4*)&Qs[d][ii0];
      const float4 kv = *(const float4*)&Ks[d][jj0];
      const float qa[4] = {qv.x, qv.y, qv.z, qv.w};
      const float kb[4] = {kv.x, kv.y, kv.z, kv.w};
#pragma unroll
      for (int a = 0; a < 4; ++a)
#pragma unroll
        for (int c2 = 0; c2 < 4; ++c2) s[a][c2] += qa[a] * kb[c2];
    }

    float rm[4], alpha[4], rs[4];
#pragma unroll
    for (int a = 0; a < 4; ++a)
      rm[a] = fmaxf(fmaxf(s[a][0], s[a][1]), fmaxf(s[a][2], s[a][3]));
#pragma unroll
    for (int msk = 1; msk <= 8; msk <<= 1) {
#pragma unroll
      for (int a = 0; a < 4; ++a) rm[a] = fmaxf(rm[a], __shfl_xor(rm[a], msk));
    }
#pragma unroll
    for (int a = 0; a < 4; ++a) {
      const float mn = fmaxf(m_i[a], rm[a]);
      alpha[a] = __expf(m_i[a] - mn);
      m_i[a] = mn;
      rs[a] = 0.f;
#pragma unroll
      for (int c2 = 0; c2 < 4; ++c2) {
        s[a][c2] = __expf(s[a][c2] - mn);
        rs[a] += s[a][c2];
      }
    }
#pragma unroll
    for (int msk = 1; msk <= 8; msk <<= 1) {
#pragma unroll
      for (int a = 0; a < 4; ++a) rs[a] += __shfl_xor(rs[a], msk);
    }
#pragma unroll
    for (int a = 0; a < 4; ++a) {
      l_i[a] = l_i[a] * alpha[a] + rs[a];
      o0a[a] *= alpha[a];
      o1a[a] *= alpha[a];
    }
#pragma unroll
    for (int c2 = 0; c2 < 4; ++c2) {
      *(float4*)&Ps[jj0 + c2][ii0] = make_float4(s[0][c2], s[1][c2], s[2][c2], s[3][c2]);
    }
    __syncthreads();
#pragma unroll 8
    for (int jj = 0; jj < BJ; ++jj) {
      const float4 pv = *(const float4*)&Ps[jj][ii0];
      const float2 vv = *(const float2*)&Vt[jj][d0];
      o0a[0] += pv.x * vv.x; o1a[0] += pv.x * vv.y;
      o0a[1] += pv.y * vv.x; o1a[1] += pv.y * vv.y;
      o0a[2] += pv.z * vv.x; o1a[2] += pv.z * vv.y;
      o0a[3] += pv.w * vv.x; o1a[3] += pv.w * vv.y;
    }
  }

  // epilogue: normalize, transpose through LDS (reuse Ps), coalesced store
  __syncthreads();
  float (*Os)[BI + 2] = (float (*)[BI + 2]) & Ps[0][0];
#pragma unroll
  for (int a = 0; a < 4; ++a) {
    const float inv = 1.f / l_i[a];
    Os[d0][ii0 + a] = o0a[a] * inv;
    Os[d0 + 1][ii0 + a] = o1a[a] * inv;
  }
  __syncthreads();
  float* op = att + ((size_t)b * HID + h * DH) * N_SP + i0;
#pragma unroll
  for (int e = 0; e < 8; ++e) {
    const int idx = e * 256 + t;
    const int d = idx >> 6, ii = idx & 63;
    op[(size_t)d * N_SP + ii] = Os[d][ii];
  }
}

// ---------------- Kernel 3: output projection + bias (fp32 in, fp32 out) ----------------
__global__ __launch_bounds__(256) void out_proj_k(
    const float* __restrict__ att,
    const float* __restrict__ w,
    const float* __restrict__ bias,
    float* __restrict__ out) {
  const int t = threadIdx.x;
  const int n0 = blockIdx.x * 512 + t * 2;
  const int o0 = blockIdx.y * 8;
  const int b = blockIdx.z;
  const float* ab = att + (size_t)b * HID * N_SP + n0;
  float acc0[8], acc1[8];
#pragma unroll
  for (int r = 0; r < 8; ++r) { acc0[r] = 0.f; acc1[r] = 0.f; }
  for (int c = 0; c < HID; c += 2) {
    const float2 a0 = *(const float2*)(ab + (size_t)c * N_SP);
    const float2 a1 = *(const float2*)(ab + (size_t)(c + 1) * N_SP);
#pragma unroll
    for (int r = 0; r < 8; ++r) {
      const float2 wv = *(const float2*)(w + (size_t)(o0 + r) * HID + c);
      acc0[r] += wv.x * a0.x + wv.y * a1.x;
      acc1[r] += wv.x * a0.y + wv.y * a1.y;
    }
  }
#pragma unroll
  for (int r = 0; r < 8; ++r) {
    const float bv = bias[o0 + r];
    *(float2*)(out + ((size_t)b * C_IN + o0 + r) * N_SP + n0) =
        make_float2(acc0[r] + bv, acc1[r] + bv);
  }
}

extern "C" void kernel_launch(void* const* d_in, const int* in_sizes, int n_in,
                              void* d_out, int out_size, void* d_ws, size_t ws_size,
                              hipStream_t stream) {
  const float* x = (const float*)d_in[0];
  const float* w_qkv = (const float*)d_in[1];
  const float* w_out = (const float*)d_in[2];
  const float* b_out = (const float*)d_in[3];
  float* out = (float*)d_out;

  float* qkv = (float*)d_ws;                              // 4*384*4096 fp32 = 25.2 MB
  float* att = qkv + (size_t)B_SZ * O_QKV * N_SP;         // 4*128*4096 fp32 =  8.4 MB

  qkv_proj_k<<<dim3(8, 48, B_SZ), 256, 0, stream>>>(x, w_qkv, qkv);
  attn_k<<<dim3(N_SP / BI, B_SZ * HEADS), 256, 0, stream>>>(qkv, att);
  out_proj_k<<<dim3(8, 32, B_SZ), 256, 0, stream>>>(att, w_out, b_out, out);
}

// Round 4
// 393.390 us; speedup vs baseline: 2.0880x; 2.0880x over previous
//
#include <hip/hip_runtime.h>
#include <hip/hip_bf16.h>
#include <stdint.h>

#define B_SZ 4
#define C_IN 256
#define N_SP 4096
#define HEADS 4
#define DH 32
#define HID 128
#define O_QKV 384

#define BI 128      // queries per block (4 waves x 32)
#define BJ 64       // keys per iteration
#define QP 36       // Q/K LDS row pitch in shorts (72B: 8B-aligned, conflict-free)
#define VP 68       // V LDS row pitch (136B)
#define PP 68       // P LDS row pitch

typedef short short4v __attribute__((ext_vector_type(4)));
typedef short short8 __attribute__((ext_vector_type(8)));
typedef short short2v __attribute__((ext_vector_type(2)));
typedef float f32x4 __attribute__((ext_vector_type(4)));

__device__ __forceinline__ short f2bf(float f) {  // RNE f32->bf16 (finite inputs)
  uint32_t u = __float_as_uint(f);
  u += 0x7fffu + ((u >> 16) & 1u);
  return (short)(u >> 16);
}

__device__ __forceinline__ short8 ld_frag(const short* p) {  // 8B-aligned 16B read
  short4v a = *(const short4v*)p;
  short4v b = *(const short4v*)(p + 4);
  return __builtin_shufflevector(a, b, 0, 1, 2, 3, 4, 5, 6, 7);
}
__device__ __forceinline__ void st8(short* p, short8 v) {  // 8B-aligned 16B write
  *(short4v*)p = __builtin_shufflevector(v, v, 0, 1, 2, 3);
  *(short4v*)(p + 4) = __builtin_shufflevector(v, v, 4, 5, 6, 7);
}
__device__ __forceinline__ f32x4 mfma16(short8 a, short8 b, f32x4 c) {
  return __builtin_amdgcn_mfma_f32_16x16x32_bf16(a, b, c, 0, 0, 0);
}

// ---------------- Kernel 1: QKV projection (fp32 in -> bf16 ws, MFMA-ready layouts) ----
// qt[bh][n][32] (scale*log2e folded), kt[bh][n][32], vt[bh][32][n]
__global__ __launch_bounds__(256) void qkv_proj_k(
    const float* __restrict__ x, const float* __restrict__ w,
    short* __restrict__ qt, short* __restrict__ kt, short* __restrict__ vt) {
  const int t = threadIdx.x;
  const int n0 = blockIdx.x * 512 + t * 2;
  const int o0 = blockIdx.y * 8;  // global output row in [0,384)
  const int b = blockIdx.z;
  const float* xb = x + (size_t)b * C_IN * N_SP + n0;
  float acc0[8], acc1[8];
#pragma unroll
  for (int r = 0; r < 8; ++r) { acc0[r] = 0.f; acc1[r] = 0.f; }
  for (int c = 0; c < C_IN; c += 2) {
    const float2 xa = *(const float2*)(xb + (size_t)c * N_SP);
    const float2 xc = *(const float2*)(xb + (size_t)(c + 1) * N_SP);
#pragma unroll
    for (int r = 0; r < 8; ++r) {
      const float2 wv = *(const float2*)(w + (size_t)(o0 + r) * C_IN + c);
      acc0[r] += wv.x * xa.x + wv.y * xc.x;
      acc1[r] += wv.x * xa.y + wv.y * xc.y;
    }
  }
  const int h_all = o0 >> 5;          // 0..11
  const int sect = h_all >> 2;        // 0=Q 1=K 2=V
  const int h = h_all & 3, d0 = o0 & 31;
  const int bh = b * HEADS + h;
  if (sect == 0) {
    const float SL = 0.17677669529663687f * 1.4426950408889634f;  // scale * log2(e)
    short8 p0, p1;
#pragma unroll
    for (int r = 0; r < 8; ++r) { p0[r] = f2bf(acc0[r] * SL); p1[r] = f2bf(acc1[r] * SL); }
    short* dst = qt + ((size_t)bh * N_SP + n0) * DH + d0;
    *(short8*)dst = p0;           // 16B-aligned (d0 multiple of 8)
    *(short8*)(dst + DH) = p1;
  } else if (sect == 1) {
    short8 p0, p1;
#pragma unroll
    for (int r = 0; r < 8; ++r) { p0[r] = f2bf(acc0[r]); p1[r] = f2bf(acc1[r]); }
    short* dst = kt + ((size_t)bh * N_SP + n0) * DH + d0;
    *(short8*)dst = p0;
    *(short8*)(dst + DH) = p1;
  } else {
#pragma unroll
    for (int r = 0; r < 8; ++r) {
      short2v pv; pv[0] = f2bf(acc0[r]); pv[1] = f2bf(acc1[r]);
      *(short2v*)(vt + ((size_t)bh * DH + d0 + r) * N_SP + n0) = pv;
    }
  }
}

// ---------------- Kernel 2: flash attention, bf16 MFMA core ----------------
__global__ __launch_bounds__(256, 2) void attn_k(
    const short* __restrict__ qt, const short* __restrict__ kt,
    const short* __restrict__ vt, float* __restrict__ att) {
  __shared__ short Qs[BI * QP];   // 9216 B   [i][d]
  __shared__ short Ks[BJ * QP];   // 4608 B   [j][d]
  __shared__ short Vs[DH * VP];   // 4352 B   [d][j]
  __shared__ short Ps[BI * PP];   // 17408 B  [i][j] bf16 P
  const int t = threadIdx.x;
  const int lane = t & 63, w = t >> 6;
  const int l15 = lane & 15, quad = lane >> 4;
  const int i0 = blockIdx.x * BI;
  const int bh = blockIdx.y;
  const short* qg = qt + ((size_t)bh * N_SP + i0) * DH;
  const short* kg = kt + (size_t)bh * N_SP * DH;
  const short* vg = vt + (size_t)bh * DH * N_SP;

  // stage Q (one-time): 128 rows x 64B
  {
    const int r = t >> 1, hf = t & 1;
    const short* src = qg + r * DH + hf * 16;
    short* dst = Qs + r * QP + hf * 16;
    short8 v0 = *(const short8*)src;
    short8 v1 = *(const short8*)(src + 8);
    st8(dst, v0); st8(dst + 8, v1);
  }

  f32x4 zz = {0.f, 0.f, 0.f, 0.f};
  f32x4 o_acc[2][2] = {{zz, zz}, {zz, zz}};  // [tt][dt]
  float m_i[2][4], l_i[2][4];
#pragma unroll
  for (int tt = 0; tt < 2; ++tt)
#pragma unroll
    for (int r = 0; r < 4; ++r) { m_i[tt][r] = -1e30f; l_i[tt][r] = 0.f; }

  for (int jt0 = 0; jt0 < N_SP; jt0 += BJ) {
    __syncthreads();  // protect Ks/Vs (prev iter readers done)
    {  // stage K tile: 64 rows x 64B
      const int r = t >> 2, qr = t & 3;
      short8 kv = *(const short8*)(kg + (size_t)(jt0 + r) * DH + qr * 8);
      st8(Ks + r * QP + qr * 8, kv);
    }
    {  // stage V tile: 32 rows x 128B
      const int r = t >> 3, oc = t & 7;
      short8 vv = *(const short8*)(vg + (size_t)r * N_SP + jt0 + oc * 8);
      st8(Vs + r * VP + oc * 8, vv);
    }
    __syncthreads();

    // S = Q K^T : 16x16 tiles, K-dim = 32 = d_head, one mfma each
    short8 aq[2], bk[4];
#pragma unroll
    for (int tt = 0; tt < 2; ++tt)
      aq[tt] = ld_frag(Qs + (w * 32 + tt * 16 + l15) * QP + quad * 8);
#pragma unroll
    for (int c = 0; c < 4; ++c)
      bk[c] = ld_frag(Ks + (c * 16 + l15) * QP + quad * 8);
    f32x4 sf[2][4];
#pragma unroll
    for (int tt = 0; tt < 2; ++tt)
#pragma unroll
      for (int c = 0; c < 4; ++c) sf[tt][c] = mfma16(aq[tt], bk[c], zz);

    // online softmax (C-layout: row = quad*4+r, col = l15 + 16c); exp2 domain
    float rm[2][4], rs[2][4], al[2][4];
#pragma unroll
    for (int tt = 0; tt < 2; ++tt)
#pragma unroll
      for (int r = 0; r < 4; ++r)
        rm[tt][r] = fmaxf(fmaxf(sf[tt][0][r], sf[tt][1][r]), fmaxf(sf[tt][2][r], sf[tt][3][r]));
#pragma unroll
    for (int msk = 1; msk <= 8; msk <<= 1)
#pragma unroll
      for (int tt = 0; tt < 2; ++tt)
#pragma unroll
        for (int r = 0; r < 4; ++r) rm[tt][r] = fmaxf(rm[tt][r], __shfl_xor(rm[tt][r], msk));
#pragma unroll
    for (int tt = 0; tt < 2; ++tt)
#pragma unroll
      for (int r = 0; r < 4; ++r) {
        const float mn = fmaxf(m_i[tt][r], rm[tt][r]);
        al[tt][r] = exp2f(m_i[tt][r] - mn);
        m_i[tt][r] = mn;
        float s0 = 0.f;
#pragma unroll
        for (int c = 0; c < 4; ++c) {
          const float e = exp2f(sf[tt][c][r] - mn);
          sf[tt][c][r] = e; s0 += e;
        }
        rs[tt][r] = s0;
      }
#pragma unroll
    for (int msk = 1; msk <= 8; msk <<= 1)
#pragma unroll
      for (int tt = 0; tt < 2; ++tt)
#pragma unroll
        for (int r = 0; r < 4; ++r) rs[tt][r] += __shfl_xor(rs[tt][r], msk);
#pragma unroll
    for (int tt = 0; tt < 2; ++tt)
#pragma unroll
      for (int r = 0; r < 4; ++r) {
        l_i[tt][r] = l_i[tt][r] * al[tt][r] + rs[tt][r];
#pragma unroll
        for (int dt = 0; dt < 2; ++dt) o_acc[tt][dt][r] *= al[tt][r];
      }

    // P -> LDS (bf16, [i][j]); own-wave rows only, no barrier needed
#pragma unroll
    for (int tt = 0; tt < 2; ++tt)
#pragma unroll
      for (int r = 0; r < 4; ++r)
#pragma unroll
        for (int c = 0; c < 4; ++c)
          Ps[(w * 32 + tt * 16 + quad * 4 + r) * PP + c * 16 + l15] = f2bf(sf[tt][c][r]);
    asm volatile("s_waitcnt lgkmcnt(0)" ::: "memory");  // order P write -> P read (same wave)

    // O += P V^T : A = P (rows i), B = V (Vs[d][j], k=j contiguous)
    short8 pa[2][2], vb[2][2];
#pragma unroll
    for (int tt = 0; tt < 2; ++tt)
#pragma unroll
      for (int kk = 0; kk < 2; ++kk)
        pa[tt][kk] = ld_frag(Ps + (w * 32 + tt * 16 + l15) * PP + kk * 32 + quad * 8);
#pragma unroll
    for (int dt = 0; dt < 2; ++dt)
#pragma unroll
      for (int kk = 0; kk < 2; ++kk)
        vb[dt][kk] = ld_frag(Vs + (dt * 16 + l15) * VP + kk * 32 + quad * 8);
#pragma unroll
    for (int tt = 0; tt < 2; ++tt)
#pragma unroll
      for (int dt = 0; dt < 2; ++dt) {
        o_acc[tt][dt] = mfma16(pa[tt][0], vb[dt][0], o_acc[tt][dt]);
        o_acc[tt][dt] = mfma16(pa[tt][1], vb[dt][1], o_acc[tt][dt]);
      }
  }

  // epilogue: normalize, transpose through LDS, coalesced fp32 store to att[bh*32+d][n]
  __syncthreads();
  float* Osh = (float*)Ps;  // [d][i], pitch 132 floats (16896 B <= 17408)
  const int OP = 132;
#pragma unroll
  for (int tt = 0; tt < 2; ++tt)
#pragma unroll
    for (int r = 0; r < 4; ++r) {
      const float inv = 1.f / l_i[tt][r];
      const int i = w * 32 + tt * 16 + quad * 4 + r;
#pragma unroll
      for (int dt = 0; dt < 2; ++dt)
        Osh[(l15 + 16 * dt) * OP + i] = o_acc[tt][dt][r] * inv;
    }
  __syncthreads();
  {
    const int d = t >> 3, ch = t & 7;
    float* dst = att + ((size_t)bh * DH + d) * N_SP + i0 + ch * 16;
    const float* src = Osh + d * OP + ch * 16;
#pragma unroll
    for (int k = 0; k < 4; ++k) *(float4*)(dst + k * 4) = *(const float4*)(src + k * 4);
  }
}

// ---------------- Kernel 3: output projection + bias (fp32 in, fp32 out) ----------------
__global__ __launch_bounds__(256) void out_proj_k(
    const float* __restrict__ att, const float* __restrict__ w,
    const float* __restrict__ bias, float* __restrict__ out) {
  const int t = threadIdx.x;
  const int n0 = blockIdx.x * 512 + t * 2;
  const int o0 = blockIdx.y * 8;
  const int b = blockIdx.z;
  const float* ab = att + (size_t)b * HID * N_SP + n0;
  float acc0[8], acc1[8];
#pragma unroll
  for (int r = 0; r < 8; ++r) { acc0[r] = 0.f; acc1[r] = 0.f; }
  for (int c = 0; c < HID; c += 2) {
    const float2 a0 = *(const float2*)(ab + (size_t)c * N_SP);
    const float2 a1 = *(const float2*)(ab + (size_t)(c + 1) * N_SP);
#pragma unroll
    for (int r = 0; r < 8; ++r) {
      const float2 wv = *(const float2*)(w + (size_t)(o0 + r) * HID + c);
      acc0[r] += wv.x * a0.x + wv.y * a1.x;
      acc1[r] += wv.x * a0.y + wv.y * a1.y;
    }
  }
#pragma unroll
  for (int r = 0; r < 8; ++r) {
    const float bv = bias[o0 + r];
    *(float2*)(out + ((size_t)b * C_IN + o0 + r) * N_SP + n0) =
        make_float2(acc0[r] + bv, acc1[r] + bv);
  }
}

extern "C" void kernel_launch(void* const* d_in, const int* in_sizes, int n_in,
                              void* d_out, int out_size, void* d_ws, size_t ws_size,
                              hipStream_t stream) {
  const float* x = (const float*)d_in[0];
  const float* w_qkv = (const float*)d_in[1];
  const float* w_out = (const float*)d_in[2];
  const float* b_out = (const float*)d_in[3];
  float* out = (float*)d_out;

  short* qt = (short*)d_ws;                                  // 16*4096*32 bf16 = 4 MB
  short* kt = qt + (size_t)16 * N_SP * DH;                   // 4 MB
  short* vt = kt + (size_t)16 * N_SP * DH;                   // 4 MB
  float* att = (float*)(vt + (size_t)16 * N_SP * DH);        // 8 MB fp32

  qkv_proj_k<<<dim3(8, 48, B_SZ), 256, 0, stream>>>(x, w_qkv, qt, kt, vt);
  attn_k<<<dim3(N_SP / BI, B_SZ * HEADS), 256, 0, stream>>>(qt, kt, vt, att);
  out_proj_k<<<dim3(8, 32, B_SZ), 256, 0, stream>>>(att, w_out, b_out, out);
}

// Round 5
// 321.105 us; speedup vs baseline: 2.5580x; 1.2251x over previous
//
#include <hip/hip_runtime.h>
#include <hip/hip_bf16.h>
#include <stdint.h>

#define B_SZ 4
#define C_IN 256
#define N_SP 4096
#define HEADS 4
#define DH 32
#define HID 128
#define O_QKV 384

#define BI 64       // queries per block (4 waves x 16)
#define BJ 64       // keys per iteration
#define PP 68       // P LDS row pitch in shorts (136 B)

typedef short short4v __attribute__((ext_vector_type(4)));
typedef short short8 __attribute__((ext_vector_type(8)));
typedef float f32x4 __attribute__((ext_vector_type(4)));

__device__ __forceinline__ short f2bf(float f) {  // RNE f32->bf16 (finite inputs)
  uint32_t u = __float_as_uint(f);
  u += 0x7fffu + ((u >> 16) & 1u);
  return (short)(u >> 16);
}
__device__ __forceinline__ short8 ld_frag(const short* p) {  // 8B-aligned 16B LDS read
  short4v a = *(const short4v*)p;
  short4v b = *(const short4v*)(p + 4);
  return __builtin_shufflevector(a, b, 0, 1, 2, 3, 4, 5, 6, 7);
}
__device__ __forceinline__ f32x4 mfma16(short8 a, short8 b, f32x4 c) {
  return __builtin_amdgcn_mfma_f32_16x16x32_bf16(a, b, c, 0, 0, 0);
}

// ---------------- Kernel 1: QKV projection (fp32 in -> bf16 ws, MFMA-ready layouts) ----
// qt[bh][n][32] (scale*log2e folded), kt[bh][n][32], vt[bh][32][n]
__global__ __launch_bounds__(256) void qkv_proj_k(
    const float* __restrict__ x, const float* __restrict__ w,
    short* __restrict__ qt, short* __restrict__ kt, short* __restrict__ vt) {
  const int t = threadIdx.x;
  const int n0 = blockIdx.x * 1024 + t * 4;
  const int o0 = blockIdx.y * 8;  // output row in [0,384)
  const int b = blockIdx.z;
  const float* xb = x + (size_t)b * C_IN * N_SP + n0;
  float acc[8][4];
#pragma unroll
  for (int r = 0; r < 8; ++r)
#pragma unroll
    for (int j = 0; j < 4; ++j) acc[r][j] = 0.f;
  for (int c = 0; c < C_IN; c += 2) {
    const float4 xa = *(const float4*)(xb + (size_t)c * N_SP);
    const float4 xc = *(const float4*)(xb + (size_t)(c + 1) * N_SP);
    const float xaj[4] = {xa.x, xa.y, xa.z, xa.w};
    const float xcj[4] = {xc.x, xc.y, xc.z, xc.w};
#pragma unroll
    for (int r = 0; r < 8; ++r) {
      const float2 wv = *(const float2*)(w + (size_t)(o0 + r) * C_IN + c);
#pragma unroll
      for (int j = 0; j < 4; ++j) acc[r][j] += wv.x * xaj[j] + wv.y * xcj[j];
    }
  }
  const int h_all = o0 >> 5;          // 0..11
  const int sect = h_all >> 2;        // 0=Q 1=K 2=V
  const int h = h_all & 3, d0 = o0 & 31;
  const int bh = b * HEADS + h;
  if (sect == 0) {
    const float SL = 0.17677669529663687f * 1.4426950408889634f;  // scale * log2(e)
#pragma unroll
    for (int j = 0; j < 4; ++j) {
      short8 p;
#pragma unroll
      for (int r = 0; r < 8; ++r) p[r] = f2bf(acc[r][j] * SL);
      *(short8*)(qt + ((size_t)bh * N_SP + n0 + j) * DH + d0) = p;
    }
  } else if (sect == 1) {
#pragma unroll
    for (int j = 0; j < 4; ++j) {
      short8 p;
#pragma unroll
      for (int r = 0; r < 8; ++r) p[r] = f2bf(acc[r][j]);
      *(short8*)(kt + ((size_t)bh * N_SP + n0 + j) * DH + d0) = p;
    }
  } else {
#pragma unroll
    for (int r = 0; r < 8; ++r) {
      short4v p;
#pragma unroll
      for (int j = 0; j < 4; ++j) p[j] = f2bf(acc[r][j]);
      *(short4v*)(vt + ((size_t)bh * DH + d0 + r) * N_SP + n0) = p;
    }
  }
}

// ---------------- Kernel 2: flash attention, bf16 MFMA, no-barrier loop ----------------
// S^T formulation: mfma(K,Q) -> lane holds S[j=quad*4+r][i=l15]; no-max softmax;
// P round-trip through per-wave LDS rows; K/V fragments direct from global.
__global__ __launch_bounds__(256, 4) void attn_k(
    const short* __restrict__ qt, const short* __restrict__ kt,
    const short* __restrict__ vt, float* __restrict__ att) {
  __shared__ short Ps[BI * PP];     // 8704 B, [i][j] bf16, rows owned per-wave
  __shared__ float Osh[DH * 68];    // 8704 B, epilogue transpose
  const int t = threadIdx.x;
  const int lane = t & 63, w = t >> 6;
  const int l15 = lane & 15, quad = lane >> 4;
  const int i0 = blockIdx.x * BI;
  const int bh = blockIdx.y;
  const short* qg = qt + ((size_t)bh * N_SP + i0) * DH;
  const short* kg = kt + (size_t)bh * N_SP * DH;
  const short* vg = vt + (size_t)bh * DH * N_SP;

  // Q fragment: loop-invariant, one 16B global read per lane
  const short8 bq = *(const short8*)(qg + (size_t)(w * 16 + l15) * DH + quad * 8);

  const f32x4 zz = {0.f, 0.f, 0.f, 0.f};
  f32x4 o_acc[2] = {zz, zz};   // [dt]: D[m=i=quad*4+r][n=d=l15+16dt]
  float lsum = 0.f;            // partial row-sum for i=l15 (this lane's quad subset of j)
  short* prow = Ps + (w * 16 + l15) * PP;

  for (int jt0 = 0; jt0 < N_SP; jt0 += BJ) {
    // K fragments: A[m=j][k=d]; 16 rows x 64B = 1KB coalesced per load
    short8 ak[4];
#pragma unroll
    for (int jt = 0; jt < 4; ++jt)
      ak[jt] = *(const short8*)(kg + (size_t)(jt0 + jt * 16 + l15) * DH + quad * 8);
    // V fragments: B[n=d][k=j] from vt[d][n]
    short8 vb[2][2];
#pragma unroll
    for (int dt = 0; dt < 2; ++dt)
#pragma unroll
      for (int kk = 0; kk < 2; ++kk)
        vb[dt][kk] = *(const short8*)(vg + (size_t)(dt * 16 + l15) * N_SP + jt0 + kk * 32 + quad * 8);

    // S^T tiles: D[j][i]
    f32x4 sf[4];
#pragma unroll
    for (int jt = 0; jt < 4; ++jt) sf[jt] = mfma16(ak[jt], bq, zz);

    // exp2 (no max), accumulate l, pack P[i][j] (4 consecutive j per write)
#pragma unroll
    for (int jt = 0; jt < 4; ++jt) {
      short4v pk;
#pragma unroll
      for (int r = 0; r < 4; ++r) {
        const float e = exp2f(sf[jt][r]);
        lsum += e;
        pk[r] = f2bf(e);
      }
      *(short4v*)(prow + jt * 16 + quad * 4) = pk;
    }
    asm volatile("s_waitcnt lgkmcnt(0)" ::: "memory");  // same-wave P write->read ordering

    // O += P V^T
    short8 pa[2];
#pragma unroll
    for (int kk = 0; kk < 2; ++kk) pa[kk] = ld_frag(prow + kk * 32 + quad * 8);
#pragma unroll
    for (int dt = 0; dt < 2; ++dt) {
      o_acc[dt] = mfma16(pa[0], vb[dt][0], o_acc[dt]);
      o_acc[dt] = mfma16(pa[1], vb[dt][1], o_acc[dt]);
    }
  }

  // finalize l: reduce over quads (lanes sharing l15)
  lsum += __shfl_xor(lsum, 16);
  lsum += __shfl_xor(lsum, 32);
  // o_acc rows are i=quad*4+r -> fetch matching l
  float linv[4];
#pragma unroll
  for (int r = 0; r < 4; ++r) linv[r] = 1.f / __shfl(lsum, quad * 4 + r);
  // normalize + transpose to Osh[d][i]
#pragma unroll
  for (int dt = 0; dt < 2; ++dt)
#pragma unroll
    for (int r = 0; r < 4; ++r)
      Osh[(dt * 16 + l15) * 68 + w * 16 + quad * 4 + r] = o_acc[dt][r] * linv[r];
  __syncthreads();
  {  // coalesced store: att[bh*32+d][i0..i0+63]
    const int d = t >> 3, ch = t & 7;
    float* dst = att + ((size_t)bh * DH + d) * N_SP + i0 + ch * 8;
    const float* src = Osh + d * 68 + ch * 8;
    *(float4*)dst = *(const float4*)src;
    *(float4*)(dst + 4) = *(const float4*)(src + 4);
  }
}

// ---------------- Kernel 3: output projection + bias (fp32 in, fp32 out) ----------------
__global__ __launch_bounds__(256) void out_proj_k(
    const float* __restrict__ att, const float* __restrict__ w,
    const float* __restrict__ bias, float* __restrict__ out) {
  const int t = threadIdx.x;
  const int n0 = blockIdx.x * 1024 + t * 4;
  const int o0 = blockIdx.y * 8;
  const int b = blockIdx.z;
  const float* ab = att + (size_t)b * HID * N_SP + n0;
  float acc[8][4];
#pragma unroll
  for (int r = 0; r < 8; ++r)
#pragma unroll
    for (int j = 0; j < 4; ++j) acc[r][j] = 0.f;
  for (int c = 0; c < HID; c += 2) {
    const float4 a0 = *(const float4*)(ab + (size_t)c * N_SP);
    const float4 a1 = *(const float4*)(ab + (size_t)(c + 1) * N_SP);
    const float a0j[4] = {a0.x, a0.y, a0.z, a0.w};
    const float a1j[4] = {a1.x, a1.y, a1.z, a1.w};
#pragma unroll
    for (int r = 0; r < 8; ++r) {
      const float2 wv = *(const float2*)(w + (size_t)(o0 + r) * HID + c);
#pragma unroll
      for (int j = 0; j < 4; ++j) acc[r][j] += wv.x * a0j[j] + wv.y * a1j[j];
    }
  }
#pragma unroll
  for (int r = 0; r < 8; ++r) {
    const float bv = bias[o0 + r];
    *(float4*)(out + ((size_t)b * C_IN + o0 + r) * N_SP + n0) =
        make_float4(acc[r][0] + bv, acc[r][1] + bv, acc[r][2] + bv, acc[r][3] + bv);
  }
}

extern "C" void kernel_launch(void* const* d_in, const int* in_sizes, int n_in,
                              void* d_out, int out_size, void* d_ws, size_t ws_size,
                              hipStream_t stream) {
  const float* x = (const float*)d_in[0];
  const float* w_qkv = (const float*)d_in[1];
  const float* w_out = (const float*)d_in[2];
  const float* b_out = (const float*)d_in[3];
  float* out = (float*)d_out;

  short* qt = (short*)d_ws;                                  // 16*4096*32 bf16 = 4 MB
  short* kt = qt + (size_t)16 * N_SP * DH;                   // 4 MB
  short* vt = kt + (size_t)16 * N_SP * DH;                   // 4 MB
  float* att = (float*)(vt + (size_t)16 * N_SP * DH);        // 8 MB fp32

  qkv_proj_k<<<dim3(4, 48, B_SZ), 256, 0, stream>>>(x, w_qkv, qt, kt, vt);
  attn_k<<<dim3(N_SP / BI, B_SZ * HEADS), 256, 0, stream>>>(qt, kt, vt, att);
  out_proj_k<<<dim3(4, 32, B_SZ), 256, 0, stream>>>(att, w_out, b_out, out);
}

// Round 6
// 238.358 us; speedup vs baseline: 3.4460x; 1.3472x over previous
//
#include <hip/hip_runtime.h>
#include <hip/hip_bf16.h>
#include <stdint.h>

#define B_SZ 4
#define C_IN 256
#define N_SP 4096
#define HEADS 4
#define DH 32
#define HID 128

#define BI 128      // queries per block (4 waves x 32)
#define BJ 64       // keys per iteration
#define PP 68       // P LDS row pitch in shorts (136 B, 8B-aligned, ~2-way banks)

typedef short short4v __attribute__((ext_vector_type(4)));
typedef short short8 __attribute__((ext_vector_type(8)));
typedef float f32x4 __attribute__((ext_vector_type(4)));

#if __has_builtin(__builtin_amdgcn_exp2f)
#define EXP2 __builtin_amdgcn_exp2f
#else
#define EXP2 exp2f
#endif

__device__ __forceinline__ short f2bfs(float f) {  // round-half-up f32->bf16
  return (short)((__float_as_uint(f) + 0x8000u) >> 16);
}
__device__ __forceinline__ uint32_t pk_bf(float a, float b) {  // pack 2 bf16 (a=low)
  uint32_t ua = __float_as_uint(a) + 0x8000u;
  uint32_t ub = __float_as_uint(b) + 0x8000u;
  return (ua >> 16) | (ub & 0xffff0000u);
}
__device__ __forceinline__ short8 ld_frag(const short* p) {  // 8B-aligned 16B LDS read
  short4v a = *(const short4v*)p;
  short4v b = *(const short4v*)(p + 4);
  return __builtin_shufflevector(a, b, 0, 1, 2, 3, 4, 5, 6, 7);
}
__device__ __forceinline__ f32x4 mfma16(short8 a, short8 b, f32x4 c) {
  return __builtin_amdgcn_mfma_f32_16x16x32_bf16(a, b, c, 0, 0, 0);
}

// ---------------- Kernel 1: QKV projection ----------------
// q,k -> fp32 qkf[b][o(0..255)][n] (coalesced); v -> bf16 vt[bh][d][n] (coalesced)
__global__ __launch_bounds__(256) void qkv_proj_k(
    const float* __restrict__ x, const float* __restrict__ w,
    float* __restrict__ qkf, short* __restrict__ vt) {
  const int t = threadIdx.x;
  const int n0 = blockIdx.x * 1024 + t * 4;
  const int o0 = blockIdx.y * 8;  // output row in [0,384)
  const int b = blockIdx.z;
  const float* xb = x + (size_t)b * C_IN * N_SP + n0;
  float acc[8][4];
#pragma unroll
  for (int r = 0; r < 8; ++r)
#pragma unroll
    for (int j = 0; j < 4; ++j) acc[r][j] = 0.f;
  for (int c = 0; c < C_IN; c += 2) {
    const float4 xa = *(const float4*)(xb + (size_t)c * N_SP);
    const float4 xc = *(const float4*)(xb + (size_t)(c + 1) * N_SP);
    const float xaj[4] = {xa.x, xa.y, xa.z, xa.w};
    const float xcj[4] = {xc.x, xc.y, xc.z, xc.w};
#pragma unroll
    for (int r = 0; r < 8; ++r) {
      const float2 wv = *(const float2*)(w + (size_t)(o0 + r) * C_IN + c);
#pragma unroll
      for (int j = 0; j < 4; ++j) acc[r][j] += wv.x * xaj[j] + wv.y * xcj[j];
    }
  }
  if (o0 < 256) {  // Q or K: fp32 [b][o][n], coalesced float4
    float* dst = qkf + ((size_t)b * 256 + o0) * N_SP + n0;
#pragma unroll
    for (int r = 0; r < 8; ++r)
      *(float4*)(dst + (size_t)r * N_SP) =
          make_float4(acc[r][0], acc[r][1], acc[r][2], acc[r][3]);
  } else {  // V: bf16 [bh][d][n], coalesced 8B
    const int d0 = o0 & 31, h = (o0 >> 5) & 3;
    const int bh = b * HEADS + h;
#pragma unroll
    for (int r = 0; r < 8; ++r) {
      short4v p;
#pragma unroll
      for (int j = 0; j < 4; ++j) p[j] = f2bfs(acc[r][j]);
      *(short4v*)(vt + ((size_t)bh * DH + d0 + r) * N_SP + n0) = p;
    }
  }
}

// ---------------- Kernel 1b: transpose-convert q/k: fp32 [d][n] -> bf16 [n][d] ------
// grid (16 ntile, 16 bh, 2 sect); sect 0 = Q (scale folded), 1 = K
__global__ __launch_bounds__(256) void qk_t_k(
    const float* __restrict__ qkf, short* __restrict__ qt, short* __restrict__ kt) {
  __shared__ short T[256 * 36];  // [n][d], pitch 36 shorts (72 B)
  const int t = threadIdx.x;
  const int ntile = blockIdx.x, bh = blockIdx.y, z = blockIdx.z;
  const int b = bh >> 2, h = bh & 3;
  const float sc = z ? 1.f : (0.17677669529663687f * 1.4426950408889634f);
  const float* src = qkf + ((size_t)(b * 256 + z * 128 + h * 32)) * N_SP + ntile * 256;
  {
    const int d = t >> 3, m = t & 7;
    const float* sp = src + (size_t)d * N_SP + m * 32;
#pragma unroll
    for (int k2 = 0; k2 < 8; ++k2) {
      const float4 v = *(const float4*)(sp + k2 * 4);
      const int n = m * 32 + k2 * 4;
      T[(n + 0) * 36 + d] = f2bfs(v.x * sc);
      T[(n + 1) * 36 + d] = f2bfs(v.y * sc);
      T[(n + 2) * 36 + d] = f2bfs(v.z * sc);
      T[(n + 3) * 36 + d] = f2bfs(v.w * sc);
    }
  }
  __syncthreads();
  short* dst = (z ? kt : qt) + ((size_t)bh * N_SP + ntile * 256) * DH;
  const int ch = t & 3, nb = t >> 2;
#pragma unroll
  for (int rep = 0; rep < 4; ++rep) {
    const int n = rep * 64 + nb;
    const uint2 a = *(const uint2*)&T[n * 36 + ch * 8];
    const uint2 c = *(const uint2*)&T[n * 36 + ch * 8 + 4];
    uint4 o; o.x = a.x; o.y = a.y; o.z = c.x; o.w = c.y;
    *(uint4*)(dst + (size_t)n * DH + ch * 8) = o;  // 1KB contiguous per wave
  }
}

// ---------------- Kernel 2: flash attention, bf16 MFMA, prefetched, 32 i/wave -------
__global__ __launch_bounds__(256, 2) void attn_k(
    const short* __restrict__ qt, const short* __restrict__ kt,
    const short* __restrict__ vt, float* __restrict__ att) {
  __shared__ short Ps[BI * PP];     // 17408 B, [i][j] bf16, rows owned per-wave
  __shared__ float Osh[DH * 132];   // 16896 B, epilogue transpose
  const int t = threadIdx.x;
  const int lane = t & 63, w = t >> 6;
  const int l15 = lane & 15, quad = lane >> 4;
  const int i0 = blockIdx.x * BI;
  const int bh = blockIdx.y;
  const short* qg = qt + ((size_t)bh * N_SP + i0) * DH;
  const short* kg = kt + (size_t)bh * N_SP * DH;
  const short* vg = vt + (size_t)bh * DH * N_SP;

  // Q fragments (loop-invariant): B[n=i][k=d]
  short8 bq[2];
#pragma unroll
  for (int tt = 0; tt < 2; ++tt)
    bq[tt] = *(const short8*)(qg + (size_t)(w * 32 + tt * 16 + l15) * DH + quad * 8);

  const f32x4 zz = {0.f, 0.f, 0.f, 0.f};
  f32x4 o_acc[2][2] = {{zz, zz}, {zz, zz}};  // [tt][dt]
  float lsum[2] = {0.f, 0.f};
  short* prow[2];
#pragma unroll
  for (int tt = 0; tt < 2; ++tt) prow[tt] = Ps + (w * 32 + tt * 16 + l15) * PP;

  short8 akA[4], akB[4], vbA[2][2], vbB[2][2];
#pragma unroll
  for (int jt = 0; jt < 4; ++jt)
    akA[jt] = *(const short8*)(kg + (size_t)(jt * 16 + l15) * DH + quad * 8);
#pragma unroll
  for (int dt = 0; dt < 2; ++dt)
#pragma unroll
    for (int kk = 0; kk < 2; ++kk)
      vbA[dt][kk] = *(const short8*)(vg + (size_t)(dt * 16 + l15) * N_SP + kk * 32 + quad * 8);

  auto body = [&](const short8 (&akc)[4], const short8 (&vbc)[2][2],
                  short8 (&akn)[4], short8 (&vbn)[2][2], int jn) {
    // S^T tiles: D[j][i] = mfma(K, Q)
    f32x4 sf[2][4];
#pragma unroll
    for (int tt = 0; tt < 2; ++tt)
#pragma unroll
      for (int jt = 0; jt < 4; ++jt) sf[tt][jt] = mfma16(akc[jt], bq[tt], zz);
    // prefetch next tile's K/V into the alternate register set
#pragma unroll
    for (int jt = 0; jt < 4; ++jt)
      akn[jt] = *(const short8*)(kg + (size_t)(jn + jt * 16 + l15) * DH + quad * 8);
#pragma unroll
    for (int dt = 0; dt < 2; ++dt)
#pragma unroll
      for (int kk = 0; kk < 2; ++kk)
        vbn[dt][kk] = *(const short8*)(vg + (size_t)(dt * 16 + l15) * N_SP + jn + kk * 32 + quad * 8);
    // exp2 (no max), accumulate l, pack P[i][j]
#pragma unroll
    for (int tt = 0; tt < 2; ++tt)
#pragma unroll
      for (int jt = 0; jt < 4; ++jt) {
        const float e0 = EXP2(sf[tt][jt][0]);
        const float e1 = EXP2(sf[tt][jt][1]);
        const float e2 = EXP2(sf[tt][jt][2]);
        const float e3 = EXP2(sf[tt][jt][3]);
        lsum[tt] += (e0 + e1) + (e2 + e3);
        uint2 pk; pk.x = pk_bf(e0, e1); pk.y = pk_bf(e2, e3);
        *(uint2*)(prow[tt] + jt * 16 + quad * 4) = pk;
      }
    asm volatile("s_waitcnt lgkmcnt(0)" ::: "memory");  // same-wave P write->read
    // O += P V^T
    short8 pa[2][2];
#pragma unroll
    for (int tt = 0; tt < 2; ++tt)
#pragma unroll
      for (int kk = 0; kk < 2; ++kk) pa[tt][kk] = ld_frag(prow[tt] + kk * 32 + quad * 8);
#pragma unroll
    for (int tt = 0; tt < 2; ++tt)
#pragma unroll
      for (int dt = 0; dt < 2; ++dt) {
        o_acc[tt][dt] = mfma16(pa[tt][0], vbc[dt][0], o_acc[tt][dt]);
        o_acc[tt][dt] = mfma16(pa[tt][1], vbc[dt][1], o_acc[tt][dt]);
      }
  };

  for (int jt0 = 0; jt0 < N_SP; jt0 += 2 * BJ) {
    body(akA, vbA, akB, vbB, (jt0 + BJ) & (N_SP - 1));
    body(akB, vbB, akA, vbA, (jt0 + 2 * BJ) & (N_SP - 1));
  }

  // finalize l: reduce over quads (lanes sharing l15)
#pragma unroll
  for (int tt = 0; tt < 2; ++tt) {
    lsum[tt] += __shfl_xor(lsum[tt], 16);
    lsum[tt] += __shfl_xor(lsum[tt], 32);
  }
  float linv[2][4];
#pragma unroll
  for (int tt = 0; tt < 2; ++tt)
#pragma unroll
    for (int r = 0; r < 4; ++r) linv[tt][r] = 1.f / __shfl(lsum[tt], quad * 4 + r);
  // normalize + transpose to Osh[d][i]
#pragma unroll
  for (int tt = 0; tt < 2; ++tt)
#pragma unroll
    for (int dt = 0; dt < 2; ++dt)
#pragma unroll
      for (int r = 0; r < 4; ++r)
        Osh[(dt * 16 + l15) * 132 + w * 32 + tt * 16 + quad * 4 + r] =
            o_acc[tt][dt][r] * linv[tt][r];
  __syncthreads();
  {  // coalesced store: att[bh*32+d][i0..i0+127]
    const int d = t >> 3, ch = t & 7;
    float* dst = att + ((size_t)bh * DH + d) * N_SP + i0 + ch * 16;
    const float* src = Osh + d * 132 + ch * 16;
#pragma unroll
    for (int k2 = 0; k2 < 4; ++k2) *(float4*)(dst + k2 * 4) = *(const float4*)(src + k2 * 4);
  }
}

// ---------------- Kernel 3: output projection + bias (fp32 in, fp32 out) ----------------
__global__ __launch_bounds__(256) void out_proj_k(
    const float* __restrict__ att, const float* __restrict__ w,
    const float* __restrict__ bias, float* __restrict__ out) {
  const int t = threadIdx.x;
  const int n0 = blockIdx.x * 1024 + t * 4;
  const int o0 = blockIdx.y * 8;
  const int b = blockIdx.z;
  const float* ab = att + (size_t)b * HID * N_SP + n0;
  float acc[8][4];
#pragma unroll
  for (int r = 0; r < 8; ++r)
#pragma unroll
    for (int j = 0; j < 4; ++j) acc[r][j] = 0.f;
  for (int c = 0; c < HID; c += 2) {
    const float4 a0 = *(const float4*)(ab + (size_t)c * N_SP);
    const float4 a1 = *(const float4*)(ab + (size_t)(c + 1) * N_SP);
    const float a0j[4] = {a0.x, a0.y, a0.z, a0.w};
    const float a1j[4] = {a1.x, a1.y, a1.z, a1.w};
#pragma unroll
    for (int r = 0; r < 8; ++r) {
      const float2 wv = *(const float2*)(w + (size_t)(o0 + r) * HID + c);
#pragma unroll
      for (int j = 0; j < 4; ++j) acc[r][j] += wv.x * a0j[j] + wv.y * a1j[j];
    }
  }
#pragma unroll
  for (int r = 0; r < 8; ++r) {
    const float bv = bias[o0 + r];
    *(float4*)(out + ((size_t)b * C_IN + o0 + r) * N_SP + n0) =
        make_float4(acc[r][0] + bv, acc[r][1] + bv, acc[r][2] + bv, acc[r][3] + bv);
  }
}

extern "C" void kernel_launch(void* const* d_in, const int* in_sizes, int n_in,
                              void* d_out, int out_size, void* d_ws, size_t ws_size,
                              hipStream_t stream) {
  const float* x = (const float*)d_in[0];
  const float* w_qkv = (const float*)d_in[1];
  const float* w_out = (const float*)d_in[2];
  const float* b_out = (const float*)d_in[3];
  float* out = (float*)d_out;

  short* qt = (short*)d_ws;                            // 16*4096*32 bf16 = 4 MB
  short* kt = qt + (size_t)16 * N_SP * DH;             // 4 MB
  short* vt = kt + (size_t)16 * N_SP * DH;             // 4 MB
  float* qkf = (float*)(vt + (size_t)16 * N_SP * DH);  // 4*256*4096 fp32 = 16.8 MB
  float* att = qkf;                                    // alias: qkf dead after qk_t_k

  qkv_proj_k<<<dim3(4, 48, B_SZ), 256, 0, stream>>>(x, w_qkv, qkf, vt);
  qk_t_k<<<dim3(16, 16, 2), 256, 0, stream>>>(qkf, qt, kt);
  attn_k<<<dim3(N_SP / BI, B_SZ * HEADS), 256, 0, stream>>>(qt, kt, vt, att);
  out_proj_k<<<dim3(4, 32, B_SZ), 256, 0, stream>>>(att, w_out, b_out, out);
}